// Round 1
// baseline (1152.248 us; speedup 1.0000x reference)
//
#include <hip/hip_runtime.h>

#define NN 50000
#define EE 800000
#define FF 128
#define DD 64
#define GG 512

// ---------------- utility kernels ----------------

__global__ void zero_k(float* __restrict__ p, int n) {
    int i = blockIdx.x * blockDim.x + threadIdx.x;
    if (i < n) p[i] = 0.f;
}

__global__ void copy_k(float* __restrict__ dst, const float* __restrict__ src, int n4) {
    for (int i = blockIdx.x * blockDim.x + threadIdx.x; i < n4; i += gridDim.x * blockDim.x)
        ((float4*)dst)[i] = ((const float4*)src)[i];
}

// ---------------- edge scatter: agg[dst] += h[src] ----------------

template<int FD>
__global__ void scatter_k(const float* __restrict__ h, const int* __restrict__ src,
                          const int* __restrict__ dst, float* __restrict__ agg) {
    constexpr int SH = (FD == 128) ? 7 : 6;
    long long total = (long long)EE * FD;
    for (long long i = (long long)blockIdx.x * blockDim.x + threadIdx.x; i < total;
         i += (long long)gridDim.x * blockDim.x) {
        int e = (int)(i >> SH);
        int f = (int)(i & (FD - 1));
        atomicAdd(&agg[(long long)dst[e] * FD + f], h[(long long)src[e] * FD + f]);
    }
}

// ---------------- skinny GEMM: out[rows x 64] = act(in[rows x K] @ W[K x 64] + b) ----------------

template<int K, bool BIAS, bool RELU>
__global__ __launch_bounds__(256) void gemm_k(const float* __restrict__ in,
                                              const float* __restrict__ W,
                                              const float* __restrict__ bias,
                                              float* __restrict__ out, int rows) {
    constexpr int KP = K + 4;  // pad to break LDS bank aliasing
    __shared__ float sW[K * 64];
    __shared__ float sIn[16 * KP];
    for (int i = threadIdx.x; i < K * 64; i += 256) sW[i] = W[i];

    int r  = threadIdx.x >> 4;   // 0..15 row within tile
    int cg = threadIdx.x & 15;   // col group
    int c0 = cg << 2;            // 4 consecutive cols
    float4 bb = make_float4(0.f, 0.f, 0.f, 0.f);
    if (BIAS) bb = *(const float4*)&bias[c0];

    for (int tile = blockIdx.x * 16; tile < rows; tile += gridDim.x * 16) {
        __syncthreads();  // covers W load on first iter + sIn reuse afterwards
        int nrows = min(16, rows - tile);
        for (int i = threadIdx.x; i < nrows * K; i += 256) {
            int rr = i / K, kk = i - rr * K;
            sIn[rr * KP + kk] = in[tile * K + i];
        }
        __syncthreads();
        if (r < nrows) {
            float4 acc = bb;
            const float* ip = &sIn[r * KP];
            const float* wp = &sW[c0];
#pragma unroll 4
            for (int k = 0; k < K; ++k) {
                float a = ip[k];
                float4 w = *(const float4*)&wp[k * 64];
                acc.x += a * w.x; acc.y += a * w.y; acc.z += a * w.z; acc.w += a * w.w;
            }
            if (RELU) {
                acc.x = fmaxf(acc.x, 0.f); acc.y = fmaxf(acc.y, 0.f);
                acc.z = fmaxf(acc.z, 0.f); acc.w = fmaxf(acc.w, 0.f);
            }
            *(float4*)&out[(tile + r) * 64 + c0] = acc;
        }
    }
}

// ---------------- batchnorm (over rows, 64 cols) ----------------

__global__ void bn_stats_k(const float* __restrict__ in, int n, float* __restrict__ stats) {
    // stats[0..63] = sum per col, stats[64..127] = sumsq per col (pre-zeroed)
    float s = 0.f, s2 = 0.f;
    int c = threadIdx.x & 63;  // stride (gridDim*256) % 64 == 0, so col is fixed
    for (int i = blockIdx.x * 256 + threadIdx.x; i < n; i += gridDim.x * 256) {
        float v = in[i];
        s += v; s2 += v * v;
    }
    __shared__ float ls[64], ls2[64];
    if (threadIdx.x < 64) { ls[threadIdx.x] = 0.f; ls2[threadIdx.x] = 0.f; }
    __syncthreads();
    atomicAdd(&ls[c], s);
    atomicAdd(&ls2[c], s2);
    __syncthreads();
    if (threadIdx.x < 64) {
        atomicAdd(&stats[threadIdx.x], ls[threadIdx.x]);
        atomicAdd(&stats[64 + threadIdx.x], ls2[threadIdx.x]);
    }
}

__global__ void bn_apply_k(const float* __restrict__ in, float* __restrict__ out, int rows,
                           const float* __restrict__ stats, const float* __restrict__ gamma,
                           const float* __restrict__ beta) {
    int n = rows * 64;
    float invr = 1.f / (float)rows;
    for (int i = blockIdx.x * blockDim.x + threadIdx.x; i < n; i += gridDim.x * blockDim.x) {
        int c = i & 63;
        float m   = stats[c] * invr;
        float var = stats[64 + c] * invr - m * m;
        out[i] = (in[i] - m) * rsqrtf(var + 1e-5f) * gamma[c] + beta[c];
    }
}

// ---------------- segment boundaries (batch is sorted) ----------------

__global__ void seg_bounds_k(const int* __restrict__ batch, int* __restrict__ segstart) {
    int g = blockIdx.x * blockDim.x + threadIdx.x;
    if (g > GG) return;
    int lo = 0, hi = NN;
    while (lo < hi) {
        int mid = (lo + hi) >> 1;
        if (batch[mid] < g) lo = mid + 1; else hi = mid;
    }
    segstart[g] = lo;
}

// ---------------- mean pooling into slots ----------------

__global__ void graph_mean_k(const float* __restrict__ h, const int* __restrict__ segstart,
                             float* __restrict__ slots) {
    int g = blockIdx.x, d = threadIdx.x;  // 64 threads
    int s0 = segstart[g], s1 = segstart[g + 1];
    float acc = 0.f;
    for (int n = s0; n < s1; ++n) acc += h[n * 64 + d];
    int cnt = s1 - s0;
    slots[g * 64 + d] = acc / (float)max(cnt, 1);
}

// ---------------- attention logits: dot(k[n], q[batch[n]]) * scale ----------------

__global__ void logits_k(const float* __restrict__ kbuf, const float* __restrict__ q,
                         const int* __restrict__ batch, float* __restrict__ logits) {
    int n = blockIdx.x * 4 + (threadIdx.x >> 6);
    int d = threadIdx.x & 63;
    if (n >= NN) return;
    int g = batch[n];
    float p = kbuf[n * 64 + d] * q[g * 64 + d];
    p += __shfl_xor(p, 1);
    p += __shfl_xor(p, 2);
    p += __shfl_xor(p, 4);
    p += __shfl_xor(p, 8);
    p += __shfl_xor(p, 16);
    p += __shfl_xor(p, 32);
    if (d == 0) logits[n] = p * 0.125f;  // 1/sqrt(64)
}

// ---------------- segment softmax + weighted sum (updates) ----------------

__global__ void softmax_updates_k(const float* __restrict__ logits, const float* __restrict__ v,
                                  const int* __restrict__ segstart, float* __restrict__ attn,
                                  float* __restrict__ updates) {
    __shared__ float red[256];
    int g = blockIdx.x;
    int s0 = segstart[g], s1 = segstart[g + 1];
    int tid = threadIdx.x;

    // 1. max
    float m = -INFINITY;
    for (int n = s0 + tid; n < s1; n += 256) m = fmaxf(m, logits[n]);
    red[tid] = m; __syncthreads();
    for (int o = 128; o > 0; o >>= 1) { if (tid < o) red[tid] = fmaxf(red[tid], red[tid + o]); __syncthreads(); }
    m = red[0]; __syncthreads();

    // 2. exp + sum
    float s = 0.f;
    for (int n = s0 + tid; n < s1; n += 256) {
        float e = expf(logits[n] - m);
        attn[n] = e;
        s += e;
    }
    red[tid] = s; __syncthreads();
    for (int o = 128; o > 0; o >>= 1) { if (tid < o) red[tid] += red[tid + o]; __syncthreads(); }
    s = red[0]; __syncthreads();
    float inv = 1.f / (s + 1e-9f);

    // 3. normalize attn
    for (int n = s0 + tid; n < s1; n += 256) attn[n] *= inv;
    __syncthreads();

    // 4. updates[g,d] = sum_n attn[n] * v[n,d]; 4 groups of 64 lanes
    int grp = tid >> 6, d = tid & 63;
    float acc = 0.f;
    for (int n = s0 + grp; n < s1; n += 4) acc += attn[n] * v[n * 64 + d];
    red[tid] = acc; __syncthreads();
    if (tid < 64) updates[g * 64 + tid] = red[tid] + red[tid + 64] + red[tid + 128] + red[tid + 192];
}

// ---------------- GRU cell: slots = GRU(updates, slots) ----------------

__global__ void gru_k(const float* __restrict__ updates, float* __restrict__ slots,
                      const float* __restrict__ Wih, const float* __restrict__ Whh,
                      const float* __restrict__ bih, const float* __restrict__ bhh) {
    __shared__ float su[64], sh[64], sgi[192], sgh[192];
    int g = blockIdx.x, tid = threadIdx.x;  // 192 threads
    if (tid < 64) { su[tid] = updates[g * 64 + tid]; sh[tid] = slots[g * 64 + tid]; }
    __syncthreads();
    {
        float a = bih[tid], b = bhh[tid];
        const float* wi = &Wih[tid * 64];
        const float* wh = &Whh[tid * 64];
#pragma unroll 8
        for (int j = 0; j < 64; ++j) { a += su[j] * wi[j]; b += sh[j] * wh[j]; }
        sgi[tid] = a; sgh[tid] = b;
    }
    __syncthreads();
    if (tid < 64) {
        float r  = 1.f / (1.f + expf(-(sgi[tid] + sgh[tid])));
        float z  = 1.f / (1.f + expf(-(sgi[64 + tid] + sgh[64 + tid])));
        float nn = tanhf(sgi[128 + tid] + r * sgh[128 + tid]);
        slots[g * 64 + tid] = (1.f - z) * nn + z * sh[tid];
    }
}

// ---------------- noisy = attn[:,None]*h + noise ----------------

__global__ void noisy_k(const float* __restrict__ h, const float* __restrict__ attn,
                        const float* __restrict__ noise, float* __restrict__ out) {
    int total = NN * 64;
    for (int i = blockIdx.x * blockDim.x + threadIdx.x; i < total; i += gridDim.x * blockDim.x) {
        int n = i >> 6;
        out[i] = attn[n] * h[i] + noise[i];
    }
}

// ---------------- host side ----------------

extern "C" void kernel_launch(void* const* d_in, const int* in_sizes, int n_in,
                              void* d_out, int out_size, void* d_ws, size_t ws_size,
                              hipStream_t stream) {
    (void)in_sizes; (void)n_in; (void)out_size; (void)ws_size;

    const float* x      = (const float*)d_in[0];
    const int*   ei     = (const int*)d_in[1];
    const int*   srcI   = ei;
    const int*   dstI   = ei + EE;
    const int*   batch  = (const int*)d_in[2];
    const float* noise  = (const float*)d_in[3];
    const float* W1_0   = (const float*)d_in[4];
    const float* b1_0   = (const float*)d_in[5];
    const float* W2_0   = (const float*)d_in[6];
    const float* b2_0   = (const float*)d_in[7];
    const float* W1_r   = (const float*)d_in[8];
    const float* b1_r   = (const float*)d_in[9];
    const float* W2_r   = (const float*)d_in[10];
    const float* b2_r   = (const float*)d_in[11];
    const float* bn_g   = (const float*)d_in[12];
    const float* bn_b   = (const float*)d_in[13];
    const float* Wq     = (const float*)d_in[14];
    const float* Wk     = (const float*)d_in[15];
    const float* Wv     = (const float*)d_in[16];
    const float* Wih    = (const float*)d_in[17];
    const float* Whh    = (const float*)d_in[18];
    const float* bih    = (const float*)d_in[19];
    const float* bhh    = (const float*)d_in[20];
    const float* nmW    = (const float*)d_in[21];
    const float* nmb    = (const float*)d_in[22];
    const float* nlW    = (const float*)d_in[23];
    const float* nlb    = (const float*)d_in[24];
    const float* gmW    = (const float*)d_in[25];
    const float* gmb    = (const float*)d_in[26];
    const float* glW    = (const float*)d_in[27];
    const float* glb    = (const float*)d_in[28];
    const float* pj_g   = (const float*)d_in[29];
    const float* pj_b   = (const float*)d_in[30];

    float* ws      = (float*)d_ws;
    float* agg0    = ws;                    // NN*FF (also reused as noisy)
    float* P1      = agg0 + NN * FF;        // NN*DD
    float* P2      = P1 + NN * DD;          // NN*DD
    float* P3      = P2 + NN * DD;          // NN*DD
    float* slots   = P3 + NN * DD;          // GG*DD
    float* updates = slots + GG * DD;       // GG*DD
    float* qbuf    = updates + GG * DD;     // GG*DD
    float* gpre    = qbuf + GG * DD;        // GG*DD
    float* logits  = gpre + GG * DD;        // NN
    float* attn    = logits + NN;           // NN
    float* stats   = attn + NN;             // 128
    int*   segst   = (int*)(stats + 128);   // GG+1

    float* outp = (float*)d_out;
    float* out_nmu = outp;
    float* out_nlv = outp + NN * DD;
    float* out_gmu = outp + 2 * NN * DD;
    float* out_glv = outp + 2 * NN * DD + GG * DD;

    // ---------- GIN layer 0 (F=128) ----------
    copy_k<<<2048, 256, 0, stream>>>(agg0, x, NN * FF / 4);
    scatter_k<128><<<(EE * 128) / 256, 256, 0, stream>>>(x, srcI, dstI, agg0);
    gemm_k<128, true, true><<<1024, 256, 0, stream>>>(agg0, W1_0, b1_0, P1, NN);
    gemm_k<64, true, true><<<1024, 256, 0, stream>>>(P1, W2_0, b2_0, P2, NN);
    zero_k<<<1, 128, 0, stream>>>(stats, 128);
    bn_stats_k<<<256, 256, 0, stream>>>(P2, NN * DD, stats);
    bn_apply_k<<<2048, 256, 0, stream>>>(P2, P2, NN, stats, bn_g + 0, bn_b + 0);

    // ---------- GIN layer 1 ----------
    copy_k<<<2048, 256, 0, stream>>>(P1, P2, NN * DD / 4);
    scatter_k<64><<<(EE * 64) / 256, 256, 0, stream>>>(P2, srcI, dstI, P1);
    gemm_k<64, true, true><<<1024, 256, 0, stream>>>(P1, W1_r, b1_r, P3, NN);
    gemm_k<64, true, true><<<1024, 256, 0, stream>>>(P3, W2_r, b2_r, P1, NN);
    zero_k<<<1, 128, 0, stream>>>(stats, 128);
    bn_stats_k<<<256, 256, 0, stream>>>(P1, NN * DD, stats);
    bn_apply_k<<<2048, 256, 0, stream>>>(P1, P1, NN, stats, bn_g + 64, bn_b + 64);

    // ---------- GIN layer 2 ----------
    copy_k<<<2048, 256, 0, stream>>>(P2, P1, NN * DD / 4);
    scatter_k<64><<<(EE * 64) / 256, 256, 0, stream>>>(P1, srcI, dstI, P2);
    gemm_k<64, true, true><<<1024, 256, 0, stream>>>(P2, W1_r + DD * DD, b1_r + DD, P3, NN);
    gemm_k<64, true, true><<<1024, 256, 0, stream>>>(P3, W2_r + DD * DD, b2_r + DD, P2, NN);
    zero_k<<<1, 128, 0, stream>>>(stats, 128);
    bn_stats_k<<<256, 256, 0, stream>>>(P2, NN * DD, stats);
    bn_apply_k<<<2048, 256, 0, stream>>>(P2, P2, NN, stats, bn_g + 128, bn_b + 128);
    // h final = P2

    // ---------- summary maker ----------
    seg_bounds_k<<<3, 256, 0, stream>>>(batch, segst);
    graph_mean_k<<<GG, 64, 0, stream>>>(P2, segst, slots);
    gemm_k<64, false, false><<<1024, 256, 0, stream>>>(P2, Wk, nullptr, P1, NN);  // k
    gemm_k<64, false, false><<<1024, 256, 0, stream>>>(P2, Wv, nullptr, P3, NN);  // v

    for (int it = 0; it < 2; ++it) {
        gemm_k<64, false, false><<<32, 256, 0, stream>>>(slots, Wq, nullptr, qbuf, GG);
        logits_k<<<NN / 4, 256, 0, stream>>>(P1, qbuf, batch, logits);
        softmax_updates_k<<<GG, 256, 0, stream>>>(logits, P3, segst, attn, updates);
        gru_k<<<GG, 192, 0, stream>>>(updates, slots, Wih, Whh, bih, bhh);
    }

    // noisy = attn*h + noise  (into agg0)
    noisy_k<<<2048, 256, 0, stream>>>(P2, attn, noise, agg0);

    // ---------- projection heads ----------
    // node_mu
    gemm_k<64, true, true><<<1024, 256, 0, stream>>>(agg0, nmW, nmb, P1, NN);
    zero_k<<<1, 128, 0, stream>>>(stats, 128);
    bn_stats_k<<<256, 256, 0, stream>>>(P1, NN * DD, stats);
    bn_apply_k<<<2048, 256, 0, stream>>>(P1, out_nmu, NN, stats, pj_g + 0, pj_b + 0);
    // node_lv
    gemm_k<64, true, true><<<1024, 256, 0, stream>>>(agg0, nlW, nlb, P1, NN);
    zero_k<<<1, 128, 0, stream>>>(stats, 128);
    bn_stats_k<<<256, 256, 0, stream>>>(P1, NN * DD, stats);
    bn_apply_k<<<2048, 256, 0, stream>>>(P1, out_nlv, NN, stats, pj_g + 64, pj_b + 64);
    // graph_mu
    gemm_k<64, true, true><<<32, 256, 0, stream>>>(slots, gmW, gmb, gpre, GG);
    zero_k<<<1, 128, 0, stream>>>(stats, 128);
    bn_stats_k<<<32, 256, 0, stream>>>(gpre, GG * DD, stats);
    bn_apply_k<<<128, 256, 0, stream>>>(gpre, out_gmu, GG, stats, pj_g + 128, pj_b + 128);
    // graph_lv
    gemm_k<64, true, true><<<32, 256, 0, stream>>>(slots, glW, glb, gpre, GG);
    zero_k<<<1, 128, 0, stream>>>(stats, 128);
    bn_stats_k<<<32, 256, 0, stream>>>(gpre, GG * DD, stats);
    bn_apply_k<<<128, 256, 0, stream>>>(gpre, out_glv, GG, stats, pj_g + 192, pj_b + 192);
}

// Round 2
// 766.858 us; speedup vs baseline: 1.5026x; 1.5026x over previous
//
#include <hip/hip_runtime.h>

#define NN 50000
#define EE 800000
#define FF 128
#define DD 64
#define GG 512

// ---------------- utility kernels ----------------

__global__ void zero_k(float* __restrict__ p, int n) {
    int i = blockIdx.x * blockDim.x + threadIdx.x;
    if (i < n) p[i] = 0.f;
}

__global__ void zero_int_k(int* __restrict__ p, int n) {
    int i = blockIdx.x * blockDim.x + threadIdx.x;
    if (i < n) p[i] = 0;
}

__global__ void copy_int_k(int* __restrict__ dst, const int* __restrict__ src, int n) {
    int i = blockIdx.x * blockDim.x + threadIdx.x;
    if (i < n) dst[i] = src[i];
}

// ---------------- CSR build (group edges by dst) ----------------

__global__ void hist_k(const int* __restrict__ dst, int* __restrict__ deg) {
    for (int e = blockIdx.x * blockDim.x + threadIdx.x; e < EE; e += gridDim.x * blockDim.x)
        atomicAdd(&deg[dst[e]], 1);
}

// single-block exclusive scan: rowstart[0]=0, rowstart[i+1]=sum(deg[0..i])
__global__ __launch_bounds__(1024) void scan_k(const int* __restrict__ deg, int* __restrict__ rowstart) {
    __shared__ int buf[1024];
    __shared__ int carry;
    int tid = threadIdx.x;
    if (tid == 0) { carry = 0; rowstart[0] = 0; }
    __syncthreads();
    for (int base = 0; base < NN; base += 1024) {
        int v = (base + tid < NN) ? deg[base + tid] : 0;
        buf[tid] = v;
        __syncthreads();
        for (int o = 1; o < 1024; o <<= 1) {
            int t = (tid >= o) ? buf[tid - o] : 0;
            __syncthreads();
            buf[tid] += t;
            __syncthreads();
        }
        if (base + tid < NN) rowstart[base + tid + 1] = carry + buf[tid];
        __syncthreads();
        if (tid == 1023) carry += buf[1023];
        __syncthreads();
    }
}

__global__ void fill_k(const int* __restrict__ src, const int* __restrict__ dst,
                       int* __restrict__ cursor, int* __restrict__ csr_src) {
    for (int e = blockIdx.x * blockDim.x + threadIdx.x; e < EE; e += gridDim.x * blockDim.x) {
        int p = atomicAdd(&cursor[dst[e]], 1);
        csr_src[p] = src[e];
    }
}

// ---------------- GIN aggregation: agg[i] = h[i] + sum_{e: dst=i} h[src[e]] ----------------

template<int FD>
__global__ __launch_bounds__(256) void gin_agg_k(const float* __restrict__ h,
                                                 const int* __restrict__ rowstart,
                                                 const int* __restrict__ csr_src,
                                                 float* __restrict__ agg) {
    int wid  = (blockIdx.x * 256 + threadIdx.x) >> 6;  // one wave per node
    int lane = threadIdx.x & 63;
    if (wid >= NN) return;
    int s0 = rowstart[wid], s1 = rowstart[wid + 1];
    float acc0 = h[wid * FD + lane];
    float acc1 = (FD == 128) ? h[wid * FD + 64 + lane] : 0.f;
    for (int e0 = s0; e0 < s1; e0 += 64) {
        int cnt  = min(64, s1 - e0);
        int srcv = (lane < cnt) ? csr_src[e0 + lane] : 0;
        for (int j = 0; j < cnt; ++j) {
            int s = __shfl(srcv, j);
            acc0 += h[s * FD + lane];
            if (FD == 128) acc1 += h[s * FD + 64 + lane];
        }
    }
    agg[wid * FD + lane] = acc0;
    if (FD == 128) agg[wid * FD + 64 + lane] = acc1;
}

// ---------------- skinny GEMM: out[rows x 64] = act(in[rows x K] @ W[K x 64] + b) ----------------

template<int K, bool BIAS, bool RELU>
__global__ __launch_bounds__(256) void gemm_k(const float* __restrict__ in,
                                              const float* __restrict__ W,
                                              const float* __restrict__ bias,
                                              float* __restrict__ out, int rows) {
    constexpr int RPT = (K == 128) ? 2 : 4;   // rows per thread
    constexpr int TR  = 16 * RPT;             // tile rows (32 or 64)
    constexpr int KP  = K + 2;                // LDS pad: 4-row reads hit distinct banks
    __shared__ float sW[K * 64];
    __shared__ float sIn[TR * KP];
    for (int i = threadIdx.x; i < K * 16; i += 256)
        ((float4*)sW)[i] = ((const float4*)W)[i];

    int rg = (threadIdx.x >> 4) * RPT;
    int c0 = (threadIdx.x & 15) << 2;
    float4 bb = make_float4(0.f, 0.f, 0.f, 0.f);
    if (BIAS) bb = *(const float4*)&bias[c0];

    for (int tile = blockIdx.x * TR; tile < rows; tile += gridDim.x * TR) {
        __syncthreads();
        int nrows = min(TR, rows - tile);
        const float4* ig = (const float4*)(in + tile * K);
        for (int i = threadIdx.x; i < nrows * (K / 4); i += 256) {
            int rr = i / (K / 4), kk = (i - rr * (K / 4)) * 4;
            float4 t = ig[i];
            float* s = &sIn[rr * KP + kk];
            s[0] = t.x; s[1] = t.y; s[2] = t.z; s[3] = t.w;
        }
        __syncthreads();
        float4 acc[RPT];
#pragma unroll
        for (int j = 0; j < RPT; ++j) acc[j] = bb;
        const float* wp = &sW[c0];
#pragma unroll 2
        for (int k = 0; k < K; ++k) {
            float4 w = *(const float4*)&wp[k * 64];
#pragma unroll
            for (int j = 0; j < RPT; ++j) {
                float a = sIn[(rg + j) * KP + k];
                acc[j].x += a * w.x; acc[j].y += a * w.y;
                acc[j].z += a * w.z; acc[j].w += a * w.w;
            }
        }
#pragma unroll
        for (int j = 0; j < RPT; ++j) {
            int r = rg + j;
            if (r < nrows) {
                float4 o = acc[j];
                if (RELU) {
                    o.x = fmaxf(o.x, 0.f); o.y = fmaxf(o.y, 0.f);
                    o.z = fmaxf(o.z, 0.f); o.w = fmaxf(o.w, 0.f);
                }
                *(float4*)&out[(tile + r) * 64 + c0] = o;
            }
        }
    }
}

// ---------------- batchnorm (over rows, 64 cols) ----------------

__global__ void bn_stats_k(const float* __restrict__ in, int n, float* __restrict__ stats) {
    float s = 0.f, s2 = 0.f;
    int c = threadIdx.x & 63;
    for (int i = blockIdx.x * 256 + threadIdx.x; i < n; i += gridDim.x * 256) {
        float v = in[i];
        s += v; s2 += v * v;
    }
    __shared__ float ls[64], ls2[64];
    if (threadIdx.x < 64) { ls[threadIdx.x] = 0.f; ls2[threadIdx.x] = 0.f; }
    __syncthreads();
    atomicAdd(&ls[c], s);
    atomicAdd(&ls2[c], s2);
    __syncthreads();
    if (threadIdx.x < 64) {
        atomicAdd(&stats[threadIdx.x], ls[threadIdx.x]);
        atomicAdd(&stats[64 + threadIdx.x], ls2[threadIdx.x]);
    }
}

__global__ void bn_apply_k(const float* __restrict__ in, float* __restrict__ out, int rows,
                           const float* __restrict__ stats, const float* __restrict__ gamma,
                           const float* __restrict__ beta) {
    int n = rows * 64;
    float invr = 1.f / (float)rows;
    for (int i = blockIdx.x * blockDim.x + threadIdx.x; i < n; i += gridDim.x * blockDim.x) {
        int c = i & 63;
        float m   = stats[c] * invr;
        float var = stats[64 + c] * invr - m * m;
        out[i] = (in[i] - m) * rsqrtf(var + 1e-5f) * gamma[c] + beta[c];
    }
}

// ---------------- segment boundaries (batch is sorted) ----------------

__global__ void seg_bounds_k(const int* __restrict__ batch, int* __restrict__ segstart) {
    int g = blockIdx.x * blockDim.x + threadIdx.x;
    if (g > GG) return;
    int lo = 0, hi = NN;
    while (lo < hi) {
        int mid = (lo + hi) >> 1;
        if (batch[mid] < g) lo = mid + 1; else hi = mid;
    }
    segstart[g] = lo;
}

// ---------------- mean pooling into slots ----------------

__global__ void graph_mean_k(const float* __restrict__ h, const int* __restrict__ segstart,
                             float* __restrict__ slots) {
    int g = blockIdx.x, d = threadIdx.x;  // 64 threads
    int s0 = segstart[g], s1 = segstart[g + 1];
    float acc = 0.f;
    for (int n = s0; n < s1; ++n) acc += h[n * 64 + d];
    int cnt = s1 - s0;
    slots[g * 64 + d] = acc / (float)max(cnt, 1);
}

// ---------------- attention logits: dot(k[n], q[batch[n]]) * scale ----------------

__global__ void logits_k(const float* __restrict__ kbuf, const float* __restrict__ q,
                         const int* __restrict__ batch, float* __restrict__ logits) {
    int n = blockIdx.x * 4 + (threadIdx.x >> 6);
    int d = threadIdx.x & 63;
    if (n >= NN) return;
    int g = batch[n];
    float p = kbuf[n * 64 + d] * q[g * 64 + d];
    p += __shfl_xor(p, 1);
    p += __shfl_xor(p, 2);
    p += __shfl_xor(p, 4);
    p += __shfl_xor(p, 8);
    p += __shfl_xor(p, 16);
    p += __shfl_xor(p, 32);
    if (d == 0) logits[n] = p * 0.125f;  // 1/sqrt(64)
}

// ---------------- segment softmax + weighted sum (updates) ----------------

__global__ void softmax_updates_k(const float* __restrict__ logits, const float* __restrict__ v,
                                  const int* __restrict__ segstart, float* __restrict__ attn,
                                  float* __restrict__ updates) {
    __shared__ float red[256];
    int g = blockIdx.x;
    int s0 = segstart[g], s1 = segstart[g + 1];
    int tid = threadIdx.x;

    float m = -INFINITY;
    for (int n = s0 + tid; n < s1; n += 256) m = fmaxf(m, logits[n]);
    red[tid] = m; __syncthreads();
    for (int o = 128; o > 0; o >>= 1) { if (tid < o) red[tid] = fmaxf(red[tid], red[tid + o]); __syncthreads(); }
    m = red[0]; __syncthreads();

    float s = 0.f;
    for (int n = s0 + tid; n < s1; n += 256) {
        float e = expf(logits[n] - m);
        attn[n] = e;
        s += e;
    }
    red[tid] = s; __syncthreads();
    for (int o = 128; o > 0; o >>= 1) { if (tid < o) red[tid] += red[tid + o]; __syncthreads(); }
    s = red[0]; __syncthreads();
    float inv = 1.f / (s + 1e-9f);

    for (int n = s0 + tid; n < s1; n += 256) attn[n] *= inv;
    __syncthreads();

    int grp = tid >> 6, d = tid & 63;
    float acc = 0.f;
    for (int n = s0 + grp; n < s1; n += 4) acc += attn[n] * v[n * 64 + d];
    red[tid] = acc; __syncthreads();
    if (tid < 64) updates[g * 64 + tid] = red[tid] + red[tid + 64] + red[tid + 128] + red[tid + 192];
}

// ---------------- GRU cell ----------------

__global__ void gru_k(const float* __restrict__ updates, float* __restrict__ slots,
                      const float* __restrict__ Wih, const float* __restrict__ Whh,
                      const float* __restrict__ bih, const float* __restrict__ bhh) {
    __shared__ float su[64], sh[64], sgi[192], sgh[192];
    int g = blockIdx.x, tid = threadIdx.x;  // 192 threads
    if (tid < 64) { su[tid] = updates[g * 64 + tid]; sh[tid] = slots[g * 64 + tid]; }
    __syncthreads();
    {
        float a = bih[tid], b = bhh[tid];
        const float* wi = &Wih[tid * 64];
        const float* wh = &Whh[tid * 64];
#pragma unroll 8
        for (int j = 0; j < 64; ++j) { a += su[j] * wi[j]; b += sh[j] * wh[j]; }
        sgi[tid] = a; sgh[tid] = b;
    }
    __syncthreads();
    if (tid < 64) {
        float r  = 1.f / (1.f + expf(-(sgi[tid] + sgh[tid])));
        float z  = 1.f / (1.f + expf(-(sgi[64 + tid] + sgh[64 + tid])));
        float nn = tanhf(sgi[128 + tid] + r * sgh[128 + tid]);
        slots[g * 64 + tid] = (1.f - z) * nn + z * sh[tid];
    }
}

// ---------------- noisy = attn[:,None]*h + noise ----------------

__global__ void noisy_k(const float* __restrict__ h, const float* __restrict__ attn,
                        const float* __restrict__ noise, float* __restrict__ out) {
    int total = NN * 64;
    for (int i = blockIdx.x * blockDim.x + threadIdx.x; i < total; i += gridDim.x * blockDim.x) {
        int n = i >> 6;
        out[i] = attn[n] * h[i] + noise[i];
    }
}

// ---------------- host side ----------------

extern "C" void kernel_launch(void* const* d_in, const int* in_sizes, int n_in,
                              void* d_out, int out_size, void* d_ws, size_t ws_size,
                              hipStream_t stream) {
    (void)in_sizes; (void)n_in; (void)out_size; (void)ws_size;

    const float* x      = (const float*)d_in[0];
    const int*   ei     = (const int*)d_in[1];
    const int*   srcI   = ei;
    const int*   dstI   = ei + EE;
    const int*   batch  = (const int*)d_in[2];
    const float* noise  = (const float*)d_in[3];
    const float* W1_0   = (const float*)d_in[4];
    const float* b1_0   = (const float*)d_in[5];
    const float* W2_0   = (const float*)d_in[6];
    const float* b2_0   = (const float*)d_in[7];
    const float* W1_r   = (const float*)d_in[8];
    const float* b1_r   = (const float*)d_in[9];
    const float* W2_r   = (const float*)d_in[10];
    const float* b2_r   = (const float*)d_in[11];
    const float* bn_g   = (const float*)d_in[12];
    const float* bn_b   = (const float*)d_in[13];
    const float* Wq     = (const float*)d_in[14];
    const float* Wk     = (const float*)d_in[15];
    const float* Wv     = (const float*)d_in[16];
    const float* Wih    = (const float*)d_in[17];
    const float* Whh    = (const float*)d_in[18];
    const float* bih    = (const float*)d_in[19];
    const float* bhh    = (const float*)d_in[20];
    const float* nmW    = (const float*)d_in[21];
    const float* nmb    = (const float*)d_in[22];
    const float* nlW    = (const float*)d_in[23];
    const float* nlb    = (const float*)d_in[24];
    const float* gmW    = (const float*)d_in[25];
    const float* gmb    = (const float*)d_in[26];
    const float* glW    = (const float*)d_in[27];
    const float* glb    = (const float*)d_in[28];
    const float* pj_g   = (const float*)d_in[29];
    const float* pj_b   = (const float*)d_in[30];

    float* ws      = (float*)d_ws;
    float* agg0    = ws;                     // NN*FF; halves T1/T2 reused later
    float* T1      = agg0;                   // NN*DD
    float* T2      = agg0 + NN * DD;         // NN*DD
    float* P1      = agg0 + NN * FF;         // NN*DD
    float* P2      = P1 + NN * DD;           // NN*DD
    float* slots   = P2 + NN * DD;           // GG*DD
    float* updates = slots + GG * DD;
    float* qbuf    = updates + GG * DD;
    float* gpre    = qbuf + GG * DD;
    float* logits  = gpre + GG * DD;         // NN
    float* attn    = logits + NN;            // NN
    float* stats   = attn + NN;              // 128
    int*   segst   = (int*)(stats + 128);    // GG+1
    int*   rowst   = segst + GG + 1;         // NN+1
    int*   cursor  = rowst + NN + 1;         // NN
    int*   csr_src = cursor + NN;            // EE

    float* outp = (float*)d_out;
    float* out_nmu = outp;
    float* out_nlv = outp + NN * DD;
    float* out_gmu = outp + 2 * NN * DD;
    float* out_glv = outp + 2 * NN * DD + GG * DD;

    // ---------- CSR build ----------
    zero_int_k<<<(NN + 255) / 256, 256, 0, stream>>>(cursor, NN);
    hist_k<<<1024, 256, 0, stream>>>(dstI, cursor);
    scan_k<<<1, 1024, 0, stream>>>(cursor, rowst);
    copy_int_k<<<(NN + 255) / 256, 256, 0, stream>>>(cursor, rowst, NN);
    fill_k<<<1024, 256, 0, stream>>>(srcI, dstI, cursor, csr_src);

    // ---------- GIN layer 0 (F=128) ----------
    gin_agg_k<128><<<(NN + 3) / 4, 256, 0, stream>>>(x, rowst, csr_src, agg0);
    gemm_k<128, true, true><<<1563, 256, 0, stream>>>(agg0, W1_0, b1_0, P1, NN);
    gemm_k<64, true, true><<<782, 256, 0, stream>>>(P1, W2_0, b2_0, P2, NN);
    zero_k<<<1, 128, 0, stream>>>(stats, 128);
    bn_stats_k<<<256, 256, 0, stream>>>(P2, NN * DD, stats);
    bn_apply_k<<<2048, 256, 0, stream>>>(P2, P2, NN, stats, bn_g + 0, bn_b + 0);

    // ---------- GIN layer 1 ----------
    gin_agg_k<64><<<(NN + 3) / 4, 256, 0, stream>>>(P2, rowst, csr_src, P1);
    gemm_k<64, true, true><<<782, 256, 0, stream>>>(P1, W1_r, b1_r, T1, NN);
    gemm_k<64, true, true><<<782, 256, 0, stream>>>(T1, W2_r, b2_r, P1, NN);
    zero_k<<<1, 128, 0, stream>>>(stats, 128);
    bn_stats_k<<<256, 256, 0, stream>>>(P1, NN * DD, stats);
    bn_apply_k<<<2048, 256, 0, stream>>>(P1, P1, NN, stats, bn_g + 64, bn_b + 64);

    // ---------- GIN layer 2 ----------
    gin_agg_k<64><<<(NN + 3) / 4, 256, 0, stream>>>(P1, rowst, csr_src, P2);
    gemm_k<64, true, true><<<782, 256, 0, stream>>>(P2, W1_r + DD * DD, b1_r + DD, T1, NN);
    gemm_k<64, true, true><<<782, 256, 0, stream>>>(T1, W2_r + DD * DD, b2_r + DD, P2, NN);
    zero_k<<<1, 128, 0, stream>>>(stats, 128);
    bn_stats_k<<<256, 256, 0, stream>>>(P2, NN * DD, stats);
    bn_apply_k<<<2048, 256, 0, stream>>>(P2, P2, NN, stats, bn_g + 128, bn_b + 128);
    // h final = P2

    // ---------- summary maker ----------
    seg_bounds_k<<<3, 256, 0, stream>>>(batch, segst);
    graph_mean_k<<<GG, 64, 0, stream>>>(P2, segst, slots);
    gemm_k<64, false, false><<<782, 256, 0, stream>>>(P2, Wk, nullptr, P1, NN);  // k
    gemm_k<64, false, false><<<782, 256, 0, stream>>>(P2, Wv, nullptr, T1, NN);  // v

    for (int it = 0; it < 2; ++it) {
        gemm_k<64, false, false><<<8, 256, 0, stream>>>(slots, Wq, nullptr, qbuf, GG);
        logits_k<<<NN / 4, 256, 0, stream>>>(P1, qbuf, batch, logits);
        softmax_updates_k<<<GG, 256, 0, stream>>>(logits, T1, segst, attn, updates);
        gru_k<<<GG, 192, 0, stream>>>(updates, slots, Wih, Whh, bih, bhh);
    }

    // noisy = attn*h + noise (into T2)
    noisy_k<<<2048, 256, 0, stream>>>(P2, attn, noise, T2);

    // ---------- projection heads ----------
    gemm_k<64, true, true><<<782, 256, 0, stream>>>(T2, nmW, nmb, P1, NN);
    zero_k<<<1, 128, 0, stream>>>(stats, 128);
    bn_stats_k<<<256, 256, 0, stream>>>(P1, NN * DD, stats);
    bn_apply_k<<<2048, 256, 0, stream>>>(P1, out_nmu, NN, stats, pj_g + 0, pj_b + 0);

    gemm_k<64, true, true><<<782, 256, 0, stream>>>(T2, nlW, nlb, P1, NN);
    zero_k<<<1, 128, 0, stream>>>(stats, 128);
    bn_stats_k<<<256, 256, 0, stream>>>(P1, NN * DD, stats);
    bn_apply_k<<<2048, 256, 0, stream>>>(P1, out_nlv, NN, stats, pj_g + 64, pj_b + 64);

    gemm_k<64, true, true><<<8, 256, 0, stream>>>(slots, gmW, gmb, gpre, GG);
    zero_k<<<1, 128, 0, stream>>>(stats, 128);
    bn_stats_k<<<32, 256, 0, stream>>>(gpre, GG * DD, stats);
    bn_apply_k<<<128, 256, 0, stream>>>(gpre, out_gmu, GG, stats, pj_g + 128, pj_b + 128);

    gemm_k<64, true, true><<<8, 256, 0, stream>>>(slots, glW, glb, gpre, GG);
    zero_k<<<1, 128, 0, stream>>>(stats, 128);
    bn_stats_k<<<32, 256, 0, stream>>>(gpre, GG * DD, stats);
    bn_apply_k<<<128, 256, 0, stream>>>(gpre, out_glv, GG, stats, pj_g + 192, pj_b + 192);
}

// Round 3
// 661.271 us; speedup vs baseline: 1.7425x; 1.1597x over previous
//
#include <hip/hip_runtime.h>

#define NN 50000
#define EE 800000
#define FF 128
#define DD 64
#define GG 512

// ---------------- init: zero cursor + all stats buffers (replay-safe) ----------------

__global__ void zero_all_k(int* __restrict__ cursor, float* __restrict__ stats_all) {
    int i = blockIdx.x * blockDim.x + threadIdx.x;
    if (i < NN) cursor[i] = 0;
    if (i < 7 * 128) stats_all[i] = 0.f;
}

// ---------------- CSR build (group edges by dst) ----------------

__global__ void hist_k(const int* __restrict__ dst, int* __restrict__ deg) {
    for (int e = blockIdx.x * blockDim.x + threadIdx.x; e < EE; e += gridDim.x * blockDim.x)
        atomicAdd(&deg[dst[e]], 1);
}

// per-1024-chunk inclusive scan; rowstart[i+1] = local inclusive, blocksum[b] = chunk total
__global__ __launch_bounds__(1024) void scanA_k(const int* __restrict__ deg,
                                                int* __restrict__ rowstart,
                                                int* __restrict__ blocksum) {
    __shared__ int buf[1024];
    int tid = threadIdx.x;
    int base = blockIdx.x * 1024;
    int v = (base + tid < NN) ? deg[base + tid] : 0;
    buf[tid] = v;
    __syncthreads();
    for (int o = 1; o < 1024; o <<= 1) {
        int t = (tid >= o) ? buf[tid - o] : 0;
        __syncthreads();
        buf[tid] += t;
        __syncthreads();
    }
    if (base + tid < NN) rowstart[base + tid + 1] = buf[tid];
    if (tid == 1023) blocksum[blockIdx.x] = buf[1023];
}

// one wave: exclusive scan of <=64 block sums
__global__ void scanB_k(const int* __restrict__ blocksum, int* __restrict__ bofs, int nb) {
    int lane = threadIdx.x;  // 64 threads
    int v = (lane < nb) ? blocksum[lane] : 0;
    int orig = v;
    for (int o = 1; o < 64; o <<= 1) {
        int t = __shfl_up(v, o);
        if (lane >= o) v += t;
    }
    if (lane < nb) bofs[lane] = v - orig;
}

// add chunk offsets; also initialize fill cursor = rowstart
__global__ void scanC_k(int* __restrict__ rowstart, const int* __restrict__ bofs,
                        int* __restrict__ cursor) {
    int i = blockIdx.x * blockDim.x + threadIdx.x;
    if (i >= NN) return;
    int val = rowstart[i + 1] + bofs[i >> 10];
    rowstart[i + 1] = val;
    if (i + 1 < NN) cursor[i + 1] = val;
    if (i == 0) { rowstart[0] = 0; cursor[0] = 0; }
}

__global__ void fill_k(const int* __restrict__ src, const int* __restrict__ dst,
                       int* __restrict__ cursor, int* __restrict__ csr_src) {
    for (int e = blockIdx.x * blockDim.x + threadIdx.x; e < EE; e += gridDim.x * blockDim.x) {
        int p = atomicAdd(&cursor[dst[e]], 1);
        csr_src[p] = src[e];
    }
}

// ---------------- GIN aggregation (layer 0, raw): agg[i] = h[i] + sum h[src] ----------------

template<int FD>
__global__ __launch_bounds__(256) void gin_agg_k(const float* __restrict__ h,
                                                 const int* __restrict__ rowstart,
                                                 const int* __restrict__ csr_src,
                                                 float* __restrict__ agg) {
    int wid  = (blockIdx.x * 256 + threadIdx.x) >> 6;  // one wave per node
    int lane = threadIdx.x & 63;
    if (wid >= NN) return;
    int s0 = rowstart[wid], s1 = rowstart[wid + 1];
    float acc0 = h[wid * FD + lane];
    float acc1 = (FD == 128) ? h[wid * FD + 64 + lane] : 0.f;
    for (int e0 = s0; e0 < s1; e0 += 64) {
        int cnt  = min(64, s1 - e0);
        int srcv = (lane < cnt) ? csr_src[e0 + lane] : 0;
        for (int j = 0; j < cnt; ++j) {
            int s = __shfl(srcv, j);
            acc0 += h[s * FD + lane];
            if (FD == 128) acc1 += h[s * FD + 64 + lane];
        }
    }
    agg[wid * FD + lane] = acc0;
    if (FD == 128) agg[wid * FD + 64 + lane] = acc1;
}

// ---------------- GIN aggregation with fused BN-apply on the input ----------------
// h' = a_c * z + d_c  (columnwise affine)  =>  agg = a_c*(z[i]+sum z[src]) + (deg+1)*d_c

__global__ __launch_bounds__(256) void gin_agg_bn_k(const float* __restrict__ z,
                                                    const int* __restrict__ rowstart,
                                                    const int* __restrict__ csr_src,
                                                    const float* __restrict__ stats,
                                                    const float* __restrict__ gamma,
                                                    const float* __restrict__ beta,
                                                    float* __restrict__ agg) {
    int wid  = (blockIdx.x * 256 + threadIdx.x) >> 6;
    int lane = threadIdx.x & 63;
    if (wid >= NN) return;
    float m   = stats[lane] * (1.f / NN);
    float var = stats[64 + lane] * (1.f / NN) - m * m;
    float a   = rsqrtf(var + 1e-5f) * gamma[lane];
    float dd  = beta[lane] - m * a;
    int s0 = rowstart[wid], s1 = rowstart[wid + 1];
    float acc = z[wid * 64 + lane];
    for (int e0 = s0; e0 < s1; e0 += 64) {
        int cnt  = min(64, s1 - e0);
        int srcv = (lane < cnt) ? csr_src[e0 + lane] : 0;
        for (int j = 0; j < cnt; ++j) {
            int s = __shfl(srcv, j);
            acc += z[s * 64 + lane];
        }
    }
    agg[wid * 64 + lane] = a * acc + (float)(s1 - s0 + 1) * dd;
}

// ---------------- skinny GEMM: out[rows x 64] = act(in[rows x K] @ W[K x 64] + b) ----------------
// STATS: accumulate per-column sum/sumsq of the stored outputs into gstats (pre-zeroed).
// ROWSCALE: input element = attn[row] * in + noise (fused "noisy" computation).

template<int K, bool BIAS, bool RELU, bool STATS, bool ROWSCALE>
__global__ __launch_bounds__(256) void gemm_k(const float* __restrict__ in,
                                              const float* __restrict__ W,
                                              const float* __restrict__ bias,
                                              float* __restrict__ out, int rows,
                                              float* __restrict__ gstats,
                                              const float* __restrict__ attn,
                                              const float* __restrict__ noise) {
    constexpr int RPT = (K == 128) ? 2 : 4;   // rows per thread
    constexpr int TR  = 16 * RPT;             // tile rows (32 or 64)
    constexpr int KP  = K + 2;
    __shared__ float sW[K * 64];
    __shared__ float sIn[TR * KP];
    __shared__ float sStat[128];
    for (int i = threadIdx.x; i < K * 16; i += 256)
        ((float4*)sW)[i] = ((const float4*)W)[i];

    int rg = (threadIdx.x >> 4) * RPT;
    int c0 = (threadIdx.x & 15) << 2;
    float4 bb = make_float4(0.f, 0.f, 0.f, 0.f);
    if (BIAS) bb = *(const float4*)&bias[c0];

    for (int tile = blockIdx.x * TR; tile < rows; tile += gridDim.x * TR) {
        __syncthreads();
        int nrows = min(TR, rows - tile);
        const float4* ig = (const float4*)(in + tile * K);
        const float4* ng = ROWSCALE ? (const float4*)(noise + tile * K) : nullptr;
        for (int i = threadIdx.x; i < nrows * (K / 4); i += 256) {
            int rr = i / (K / 4), kk = (i - rr * (K / 4)) * 4;
            float4 t = ig[i];
            if (ROWSCALE) {
                float4 nv = ng[i];
                float at = attn[tile + rr];
                t.x = at * t.x + nv.x; t.y = at * t.y + nv.y;
                t.z = at * t.z + nv.z; t.w = at * t.w + nv.w;
            }
            float* s = &sIn[rr * KP + kk];
            s[0] = t.x; s[1] = t.y; s[2] = t.z; s[3] = t.w;
        }
        __syncthreads();
        float4 acc[RPT];
#pragma unroll
        for (int j = 0; j < RPT; ++j) acc[j] = bb;
        const float* wp = &sW[c0];
#pragma unroll 2
        for (int k = 0; k < K; ++k) {
            float4 w = *(const float4*)&wp[k * 64];
#pragma unroll
            for (int j = 0; j < RPT; ++j) {
                float a = sIn[(rg + j) * KP + k];
                acc[j].x += a * w.x; acc[j].y += a * w.y;
                acc[j].z += a * w.z; acc[j].w += a * w.w;
            }
        }
        if (RELU) {
#pragma unroll
            for (int j = 0; j < RPT; ++j) {
                acc[j].x = fmaxf(acc[j].x, 0.f); acc[j].y = fmaxf(acc[j].y, 0.f);
                acc[j].z = fmaxf(acc[j].z, 0.f); acc[j].w = fmaxf(acc[j].w, 0.f);
            }
        }
#pragma unroll
        for (int j = 0; j < RPT; ++j) {
            int r = rg + j;
            if (r < nrows) *(float4*)&out[(tile + r) * 64 + c0] = acc[j];
        }
        if (STATS) {
            if (threadIdx.x < 128) sStat[threadIdx.x] = 0.f;
            __syncthreads();
            float sx = 0, sy = 0, sz = 0, sw = 0, qx = 0, qy = 0, qz = 0, qw = 0;
#pragma unroll
            for (int j = 0; j < RPT; ++j) {
                if (rg + j < nrows) {
                    sx += acc[j].x; sy += acc[j].y; sz += acc[j].z; sw += acc[j].w;
                    qx += acc[j].x * acc[j].x; qy += acc[j].y * acc[j].y;
                    qz += acc[j].z * acc[j].z; qw += acc[j].w * acc[j].w;
                }
            }
            atomicAdd(&sStat[c0 + 0], sx); atomicAdd(&sStat[c0 + 1], sy);
            atomicAdd(&sStat[c0 + 2], sz); atomicAdd(&sStat[c0 + 3], sw);
            atomicAdd(&sStat[64 + c0 + 0], qx); atomicAdd(&sStat[64 + c0 + 1], qy);
            atomicAdd(&sStat[64 + c0 + 2], qz); atomicAdd(&sStat[64 + c0 + 3], qw);
            __syncthreads();
            if (threadIdx.x < 128) atomicAdd(&gstats[threadIdx.x], sStat[threadIdx.x]);
        }
    }
}

// ---------------- batchnorm apply ----------------

__global__ void bn_apply_k(const float* __restrict__ in, float* __restrict__ out, int rows,
                           const float* __restrict__ stats, const float* __restrict__ gamma,
                           const float* __restrict__ beta) {
    int n = rows * 64;
    float invr = 1.f / (float)rows;
    for (int i = blockIdx.x * blockDim.x + threadIdx.x; i < n; i += gridDim.x * blockDim.x) {
        int c = i & 63;
        float m   = stats[c] * invr;
        float var = stats[64 + c] * invr - m * m;
        out[i] = (in[i] - m) * rsqrtf(var + 1e-5f) * gamma[c] + beta[c];
    }
}

// ---------------- segment boundaries (batch is sorted) ----------------

__global__ void seg_bounds_k(const int* __restrict__ batch, int* __restrict__ segstart) {
    int g = blockIdx.x * blockDim.x + threadIdx.x;
    if (g > GG) return;
    int lo = 0, hi = NN;
    while (lo < hi) {
        int mid = (lo + hi) >> 1;
        if (batch[mid] < g) lo = mid + 1; else hi = mid;
    }
    segstart[g] = lo;
}

// ---------------- mean pooling into slots ----------------

__global__ void graph_mean_k(const float* __restrict__ h, const int* __restrict__ segstart,
                             float* __restrict__ slots) {
    int g = blockIdx.x, d = threadIdx.x;  // 64 threads
    int s0 = segstart[g], s1 = segstart[g + 1];
    float acc = 0.f;
    for (int n = s0; n < s1; ++n) acc += h[n * 64 + d];
    int cnt = s1 - s0;
    slots[g * 64 + d] = acc / (float)max(cnt, 1);
}

// ---------------- attention logits ----------------

__global__ void logits_k(const float* __restrict__ kbuf, const float* __restrict__ q,
                         const int* __restrict__ batch, float* __restrict__ logits) {
    int n = blockIdx.x * 4 + (threadIdx.x >> 6);
    int d = threadIdx.x & 63;
    if (n >= NN) return;
    int g = batch[n];
    float p = kbuf[n * 64 + d] * q[g * 64 + d];
    p += __shfl_xor(p, 1);
    p += __shfl_xor(p, 2);
    p += __shfl_xor(p, 4);
    p += __shfl_xor(p, 8);
    p += __shfl_xor(p, 16);
    p += __shfl_xor(p, 32);
    if (d == 0) logits[n] = p * 0.125f;  // 1/sqrt(64)
}

// ---------------- segment softmax + weighted sum ----------------

__global__ void softmax_updates_k(const float* __restrict__ logits, const float* __restrict__ v,
                                  const int* __restrict__ segstart, float* __restrict__ attn,
                                  float* __restrict__ updates) {
    __shared__ float red[256];
    int g = blockIdx.x;
    int s0 = segstart[g], s1 = segstart[g + 1];
    int tid = threadIdx.x;

    float m = -INFINITY;
    for (int n = s0 + tid; n < s1; n += 256) m = fmaxf(m, logits[n]);
    red[tid] = m; __syncthreads();
    for (int o = 128; o > 0; o >>= 1) { if (tid < o) red[tid] = fmaxf(red[tid], red[tid + o]); __syncthreads(); }
    m = red[0]; __syncthreads();

    float s = 0.f;
    for (int n = s0 + tid; n < s1; n += 256) {
        float e = expf(logits[n] - m);
        attn[n] = e;
        s += e;
    }
    red[tid] = s; __syncthreads();
    for (int o = 128; o > 0; o >>= 1) { if (tid < o) red[tid] += red[tid + o]; __syncthreads(); }
    s = red[0]; __syncthreads();
    float inv = 1.f / (s + 1e-9f);

    for (int n = s0 + tid; n < s1; n += 256) attn[n] *= inv;
    __syncthreads();

    int grp = tid >> 6, d = tid & 63;
    float acc = 0.f;
    for (int n = s0 + grp; n < s1; n += 4) acc += attn[n] * v[n * 64 + d];
    red[tid] = acc; __syncthreads();
    if (tid < 64) updates[g * 64 + tid] = red[tid] + red[tid + 64] + red[tid + 128] + red[tid + 192];
}

// ---------------- GRU cell ----------------

__global__ void gru_k(const float* __restrict__ updates, float* __restrict__ slots,
                      const float* __restrict__ Wih, const float* __restrict__ Whh,
                      const float* __restrict__ bih, const float* __restrict__ bhh) {
    __shared__ float su[64], sh[64], sgi[192], sgh[192];
    int g = blockIdx.x, tid = threadIdx.x;  // 192 threads
    if (tid < 64) { su[tid] = updates[g * 64 + tid]; sh[tid] = slots[g * 64 + tid]; }
    __syncthreads();
    {
        float a = bih[tid], b = bhh[tid];
        const float* wi = &Wih[tid * 64];
        const float* wh = &Whh[tid * 64];
#pragma unroll 8
        for (int j = 0; j < 64; ++j) { a += su[j] * wi[j]; b += sh[j] * wh[j]; }
        sgi[tid] = a; sgh[tid] = b;
    }
    __syncthreads();
    if (tid < 64) {
        float r  = 1.f / (1.f + expf(-(sgi[tid] + sgh[tid])));
        float z  = 1.f / (1.f + expf(-(sgi[64 + tid] + sgh[64 + tid])));
        float nn = tanhf(sgi[128 + tid] + r * sgh[128 + tid]);
        slots[g * 64 + tid] = (1.f - z) * nn + z * sh[tid];
    }
}

// ---------------- host side ----------------

extern "C" void kernel_launch(void* const* d_in, const int* in_sizes, int n_in,
                              void* d_out, int out_size, void* d_ws, size_t ws_size,
                              hipStream_t stream) {
    (void)in_sizes; (void)n_in; (void)out_size; (void)ws_size;

    const float* x      = (const float*)d_in[0];
    const int*   ei     = (const int*)d_in[1];
    const int*   srcI   = ei;
    const int*   dstI   = ei + EE;
    const int*   batch  = (const int*)d_in[2];
    const float* noise  = (const float*)d_in[3];
    const float* W1_0   = (const float*)d_in[4];
    const float* b1_0   = (const float*)d_in[5];
    const float* W2_0   = (const float*)d_in[6];
    const float* b2_0   = (const float*)d_in[7];
    const float* W1_r   = (const float*)d_in[8];
    const float* b1_r   = (const float*)d_in[9];
    const float* W2_r   = (const float*)d_in[10];
    const float* b2_r   = (const float*)d_in[11];
    const float* bn_g   = (const float*)d_in[12];
    const float* bn_b   = (const float*)d_in[13];
    const float* Wq     = (const float*)d_in[14];
    const float* Wk     = (const float*)d_in[15];
    const float* Wv     = (const float*)d_in[16];
    const float* Wih    = (const float*)d_in[17];
    const float* Whh    = (const float*)d_in[18];
    const float* bih    = (const float*)d_in[19];
    const float* bhh    = (const float*)d_in[20];
    const float* nmW    = (const float*)d_in[21];
    const float* nmb    = (const float*)d_in[22];
    const float* nlW    = (const float*)d_in[23];
    const float* nlb    = (const float*)d_in[24];
    const float* gmW    = (const float*)d_in[25];
    const float* gmb    = (const float*)d_in[26];
    const float* glW    = (const float*)d_in[27];
    const float* glb    = (const float*)d_in[28];
    const float* pj_g   = (const float*)d_in[29];
    const float* pj_b   = (const float*)d_in[30];

    float* ws      = (float*)d_ws;
    float* agg0    = ws;                     // NN*FF; halves T1/T2 reused later
    float* T1      = agg0;                   // NN*DD
    float* T2      = agg0 + NN * DD;         // NN*DD
    float* P1      = agg0 + NN * FF;         // NN*DD
    float* P2      = P1 + NN * DD;           // NN*DD
    float* slots   = P2 + NN * DD;           // GG*DD
    float* updates = slots + GG * DD;
    float* qbuf    = updates + GG * DD;
    float* gpre    = qbuf + GG * DD;
    float* logits  = gpre + GG * DD;         // NN
    float* attn    = logits + NN;            // NN
    float* stats   = attn + NN;              // 7*128
    int*   segst   = (int*)(stats + 7 * 128); // GG+1
    int*   rowst   = segst + GG + 1;         // NN+1
    int*   cursor  = rowst + NN + 1;         // NN
    int*   bsum    = cursor + NN;            // 64
    int*   bofs    = bsum + 64;              // 64
    int*   csr_src = bofs + 64;              // EE

    float* s0 = stats, *s1 = stats + 128, *s2 = stats + 256, *s3 = stats + 384,
         * s4 = stats + 512, *s5 = stats + 640, *s6 = stats + 768;

    float* outp = (float*)d_out;
    float* out_nmu = outp;
    float* out_nlv = outp + NN * DD;
    float* out_gmu = outp + 2 * NN * DD;
    float* out_glv = outp + 2 * NN * DD + GG * DD;

    constexpr int NB = (NN + 1023) / 1024;  // 49 scan chunks

    // ---------- init + CSR build ----------
    zero_all_k<<<(NN + 255) / 256, 256, 0, stream>>>(cursor, stats);
    hist_k<<<1024, 256, 0, stream>>>(dstI, cursor);
    scanA_k<<<NB, 1024, 0, stream>>>(cursor, rowst, bsum);
    scanB_k<<<1, 64, 0, stream>>>(bsum, bofs, NB);
    scanC_k<<<(NN + 255) / 256, 256, 0, stream>>>(rowst, bofs, cursor);
    fill_k<<<1024, 256, 0, stream>>>(srcI, dstI, cursor, csr_src);

    // ---------- GIN layer 0 (F=128) ----------
    gin_agg_k<128><<<(NN + 3) / 4, 256, 0, stream>>>(x, rowst, csr_src, agg0);
    gemm_k<128, true, true, false, false><<<1563, 256, 0, stream>>>(agg0, W1_0, b1_0, P1, NN, nullptr, nullptr, nullptr);
    gemm_k<64, true, true, true, false><<<782, 256, 0, stream>>>(P1, W2_0, b2_0, P2, NN, s0, nullptr, nullptr);

    // ---------- GIN layer 1 (BN0 fused into gather) ----------
    gin_agg_bn_k<<<(NN + 3) / 4, 256, 0, stream>>>(P2, rowst, csr_src, s0, bn_g + 0, bn_b + 0, P1);
    gemm_k<64, true, true, false, false><<<782, 256, 0, stream>>>(P1, W1_r, b1_r, T1, NN, nullptr, nullptr, nullptr);
    gemm_k<64, true, true, true, false><<<782, 256, 0, stream>>>(T1, W2_r, b2_r, P2, NN, s1, nullptr, nullptr);

    // ---------- GIN layer 2 (BN1 fused into gather) ----------
    gin_agg_bn_k<<<(NN + 3) / 4, 256, 0, stream>>>(P2, rowst, csr_src, s1, bn_g + 64, bn_b + 64, P1);
    gemm_k<64, true, true, false, false><<<782, 256, 0, stream>>>(P1, W1_r + DD * DD, b1_r + DD, T1, NN, nullptr, nullptr, nullptr);
    gemm_k<64, true, true, true, false><<<782, 256, 0, stream>>>(T1, W2_r + DD * DD, b2_r + DD, P2, NN, s2, nullptr, nullptr);

    // final BN (multi-consumer) applied explicitly, in-place: P2 = h
    bn_apply_k<<<2048, 256, 0, stream>>>(P2, P2, NN, s2, bn_g + 128, bn_b + 128);

    // ---------- summary maker ----------
    seg_bounds_k<<<3, 256, 0, stream>>>(batch, segst);
    graph_mean_k<<<GG, 64, 0, stream>>>(P2, segst, slots);
    gemm_k<64, false, false, false, false><<<782, 256, 0, stream>>>(P2, Wk, nullptr, P1, NN, nullptr, nullptr, nullptr);  // k
    gemm_k<64, false, false, false, false><<<782, 256, 0, stream>>>(P2, Wv, nullptr, T1, NN, nullptr, nullptr, nullptr);  // v

    for (int it = 0; it < 2; ++it) {
        gemm_k<64, false, false, false, false><<<8, 256, 0, stream>>>(slots, Wq, nullptr, qbuf, GG, nullptr, nullptr, nullptr);
        logits_k<<<NN / 4, 256, 0, stream>>>(P1, qbuf, batch, logits);
        softmax_updates_k<<<GG, 256, 0, stream>>>(logits, T1, segst, attn, updates);
        gru_k<<<GG, 192, 0, stream>>>(updates, slots, Wih, Whh, bih, bhh);
    }

    // ---------- projection heads (noisy fused into node-head GEMMs) ----------
    gemm_k<64, true, true, true, true><<<782, 256, 0, stream>>>(P2, nmW, nmb, T2, NN, s3, attn, noise);
    bn_apply_k<<<2048, 256, 0, stream>>>(T2, out_nmu, NN, s3, pj_g + 0, pj_b + 0);

    gemm_k<64, true, true, true, true><<<782, 256, 0, stream>>>(P2, nlW, nlb, T2, NN, s4, attn, noise);
    bn_apply_k<<<2048, 256, 0, stream>>>(T2, out_nlv, NN, s4, pj_g + 64, pj_b + 64);

    gemm_k<64, true, true, true, false><<<8, 256, 0, stream>>>(slots, gmW, gmb, gpre, GG, s5, nullptr, nullptr);
    bn_apply_k<<<128, 256, 0, stream>>>(gpre, out_gmu, GG, s5, pj_g + 128, pj_b + 128);

    gemm_k<64, true, true, true, false><<<8, 256, 0, stream>>>(slots, glW, glb, gpre, GG, s6, nullptr, nullptr);
    bn_apply_k<<<128, 256, 0, stream>>>(gpre, out_glv, GG, s6, pj_g + 192, pj_b + 192);
}

// Round 4
// 512.684 us; speedup vs baseline: 2.2475x; 1.2898x over previous
//
#include <hip/hip_runtime.h>

#define NN 50000
#define EE 800000
#define FF 128
#define DD 64
#define GG 512

// ---------------- init: zero cursor + all stats buffers (replay-safe) ----------------

__global__ void zero_all_k(int* __restrict__ cursor, float* __restrict__ stats_all) {
    int i = blockIdx.x * blockDim.x + threadIdx.x;
    if (i < NN) cursor[i] = 0;
    if (i < 7 * 128) stats_all[i] = 0.f;
}

// ---------------- CSR build (counting sort by dst), 4 edges/thread ----------------

__global__ void hist_k(const int* __restrict__ dst, int* __restrict__ deg) {
    int e = (blockIdx.x * 256 + threadIdx.x) * 4;
    if (e + 4 <= EE) {
        int4 d = *(const int4*)&dst[e];
        atomicAdd(&deg[d.x], 1); atomicAdd(&deg[d.y], 1);
        atomicAdd(&deg[d.z], 1); atomicAdd(&deg[d.w], 1);
    } else {
        for (; e < EE; ++e) atomicAdd(&deg[dst[e]], 1);
    }
}

__global__ __launch_bounds__(1024) void scanA_k(const int* __restrict__ deg,
                                                int* __restrict__ rowstart,
                                                int* __restrict__ blocksum) {
    __shared__ int buf[1024];
    int tid = threadIdx.x;
    int base = blockIdx.x * 1024;
    int v = (base + tid < NN) ? deg[base + tid] : 0;
    buf[tid] = v;
    __syncthreads();
    for (int o = 1; o < 1024; o <<= 1) {
        int t = (tid >= o) ? buf[tid - o] : 0;
        __syncthreads();
        buf[tid] += t;
        __syncthreads();
    }
    if (base + tid < NN) rowstart[base + tid + 1] = buf[tid];
    if (tid == 1023) blocksum[blockIdx.x] = buf[1023];
}

__global__ void scanB_k(const int* __restrict__ blocksum, int* __restrict__ bofs, int nb) {
    int lane = threadIdx.x;  // 64 threads
    int v = (lane < nb) ? blocksum[lane] : 0;
    int orig = v;
    for (int o = 1; o < 64; o <<= 1) {
        int t = __shfl_up(v, o);
        if (lane >= o) v += t;
    }
    if (lane < nb) bofs[lane] = v - orig;
}

__global__ void scanC_k(int* __restrict__ rowstart, const int* __restrict__ bofs,
                        int* __restrict__ cursor) {
    int i = blockIdx.x * blockDim.x + threadIdx.x;
    if (i >= NN) return;
    int val = rowstart[i + 1] + bofs[i >> 10];
    rowstart[i + 1] = val;
    if (i + 1 < NN) cursor[i + 1] = val;
    if (i == 0) { rowstart[0] = 0; cursor[0] = 0; }
}

__global__ void fill_k(const int* __restrict__ src, const int* __restrict__ dst,
                       int* __restrict__ cursor, int* __restrict__ csr_src) {
    int e = (blockIdx.x * 256 + threadIdx.x) * 4;
    if (e + 4 <= EE) {
        int4 d = *(const int4*)&dst[e];
        int4 s = *(const int4*)&src[e];
        int p0 = atomicAdd(&cursor[d.x], 1);
        int p1 = atomicAdd(&cursor[d.y], 1);
        int p2 = atomicAdd(&cursor[d.z], 1);
        int p3 = atomicAdd(&cursor[d.w], 1);
        csr_src[p0] = s.x; csr_src[p1] = s.y; csr_src[p2] = s.z; csr_src[p3] = s.w;
    } else {
        for (; e < EE; ++e) { int p = atomicAdd(&cursor[dst[e]], 1); csr_src[p] = src[e]; }
    }
}

// ---------------- GIN aggregation, 16 lanes/node, float4: out = relu(in[i]+sum in[src]+bias) ----------------

__global__ __launch_bounds__(256) void gin_agg_br_k(const float* __restrict__ in,
                                                    const int* __restrict__ rowstart,
                                                    const int* __restrict__ csr_src,
                                                    const float* __restrict__ bias,
                                                    float* __restrict__ out) {
    int gt    = blockIdx.x * 256 + threadIdx.x;
    int node  = gt >> 4;          // 4 nodes per wave, 16 lanes each
    int l16   = threadIdx.x & 15;
    int gbase = threadIdx.x & 48; // group base lane within wave
    int s0 = rowstart[node], s1 = rowstart[node + 1];
    float4 acc = ((const float4*)in)[node * 16 + l16];
    for (int e0 = s0; e0 < s1; e0 += 16) {
        int cnt  = min(16, s1 - e0);
        int srcv = (l16 < cnt) ? csr_src[e0 + l16] : 0;
        for (int j = 0; j < cnt; ++j) {
            int s = __shfl(srcv, gbase + j);
            float4 hv = ((const float4*)in)[s * 16 + l16];
            acc.x += hv.x; acc.y += hv.y; acc.z += hv.z; acc.w += hv.w;
        }
    }
    float4 b = ((const float4*)bias)[l16];
    acc.x = fmaxf(acc.x + b.x, 0.f); acc.y = fmaxf(acc.y + b.y, 0.f);
    acc.z = fmaxf(acc.z + b.z, 0.f); acc.w = fmaxf(acc.w + b.w, 0.f);
    ((float4*)out)[node * 16 + l16] = acc;
}

// ---------------- unified skinny GEMM ----------------
// out[rows x 64] = act(T(in)[rows x K] @ W + b), T = optional BN-affine (BNIN) then
// rowscale+noise (ROWSCALE). DUAL: second weight/bias/out sharing the same input pass.
// STATS: per-column sum/sumsq of stored outputs accumulated into gstats (pre-zeroed).

template<int K, bool BIAS, bool RELU, bool STATS, bool ROWSCALE, bool BNIN, bool DUAL>
__global__ __launch_bounds__(256) void gemm_k(
    const float* __restrict__ in, const float* __restrict__ W, const float* __restrict__ Wb,
    const float* __restrict__ bias, const float* __restrict__ bias2,
    float* __restrict__ out, float* __restrict__ out2, int rows,
    float* __restrict__ gstats, float* __restrict__ gstats2,
    const float* __restrict__ attn, const float* __restrict__ noise,
    const float* __restrict__ bnstats, const float* __restrict__ gamma,
    const float* __restrict__ beta)
{
    constexpr int RPT = (K == 128) ? 2 : 4;
    constexpr int TR  = 16 * RPT;
    constexpr int KP  = K + 2;
    constexpr int SS  = DUAL ? 256 : 128;
    __shared__ float sW[K * 64];
    __shared__ float sWb[DUAL ? K * 64 : 4];
    __shared__ float sIn[TR * KP];
    __shared__ float sStat[STATS ? SS : 4];
    __shared__ float sA[BNIN ? 64 : 4];
    __shared__ float sD[BNIN ? 64 : 4];

    for (int i = threadIdx.x; i < K * 16; i += 256) ((float4*)sW)[i] = ((const float4*)W)[i];
    if (DUAL)
        for (int i = threadIdx.x; i < K * 16; i += 256) ((float4*)sWb)[i] = ((const float4*)Wb)[i];
    if (BNIN && threadIdx.x < 64) {
        float m   = bnstats[threadIdx.x] * (1.f / NN);
        float var = bnstats[64 + threadIdx.x] * (1.f / NN) - m * m;
        float a   = rsqrtf(var + 1e-5f) * gamma[threadIdx.x];
        sA[threadIdx.x] = a;
        sD[threadIdx.x] = beta[threadIdx.x] - m * a;
    }

    int rg = (threadIdx.x >> 4) * RPT;
    int c0 = (threadIdx.x & 15) << 2;
    float4 bb  = make_float4(0.f, 0.f, 0.f, 0.f);
    float4 bb2 = make_float4(0.f, 0.f, 0.f, 0.f);
    if (BIAS) bb = *(const float4*)&bias[c0];
    if (BIAS && DUAL) bb2 = *(const float4*)&bias2[c0];

    for (int tile = blockIdx.x * TR; tile < rows; tile += gridDim.x * TR) {
        __syncthreads();
        int nrows = min(TR, rows - tile);
        const float4* ig = (const float4*)(in + tile * K);
        const float4* ng = ROWSCALE ? (const float4*)(noise + tile * K) : nullptr;
        for (int i = threadIdx.x; i < nrows * (K / 4); i += 256) {
            int rr = i / (K / 4), kk = (i - rr * (K / 4)) * 4;
            float4 t = ig[i];
            if (BNIN) {
                t.x = sA[kk + 0] * t.x + sD[kk + 0];
                t.y = sA[kk + 1] * t.y + sD[kk + 1];
                t.z = sA[kk + 2] * t.z + sD[kk + 2];
                t.w = sA[kk + 3] * t.w + sD[kk + 3];
            }
            if (ROWSCALE) {
                float4 nv = ng[i];
                float at = attn[tile + rr];
                t.x = at * t.x + nv.x; t.y = at * t.y + nv.y;
                t.z = at * t.z + nv.z; t.w = at * t.w + nv.w;
            }
            float* s = &sIn[rr * KP + kk];
            s[0] = t.x; s[1] = t.y; s[2] = t.z; s[3] = t.w;
        }
        __syncthreads();
        float4 acc[RPT];
        float4 acc2[DUAL ? RPT : 1];
#pragma unroll
        for (int j = 0; j < RPT; ++j) acc[j] = bb;
        if (DUAL) {
#pragma unroll
            for (int j = 0; j < RPT; ++j) acc2[j] = bb2;
        }
        const float* wp  = &sW[c0];
        const float* wp2 = &sWb[c0];
#pragma unroll 2
        for (int k = 0; k < K; ++k) {
            float4 w = *(const float4*)&wp[k * 64];
            float4 w2;
            if (DUAL) w2 = *(const float4*)&wp2[k * 64];
#pragma unroll
            for (int j = 0; j < RPT; ++j) {
                float a = sIn[(rg + j) * KP + k];
                acc[j].x += a * w.x; acc[j].y += a * w.y;
                acc[j].z += a * w.z; acc[j].w += a * w.w;
                if (DUAL) {
                    acc2[j].x += a * w2.x; acc2[j].y += a * w2.y;
                    acc2[j].z += a * w2.z; acc2[j].w += a * w2.w;
                }
            }
        }
        if (RELU) {
#pragma unroll
            for (int j = 0; j < RPT; ++j) {
                acc[j].x = fmaxf(acc[j].x, 0.f); acc[j].y = fmaxf(acc[j].y, 0.f);
                acc[j].z = fmaxf(acc[j].z, 0.f); acc[j].w = fmaxf(acc[j].w, 0.f);
                if (DUAL) {
                    acc2[j].x = fmaxf(acc2[j].x, 0.f); acc2[j].y = fmaxf(acc2[j].y, 0.f);
                    acc2[j].z = fmaxf(acc2[j].z, 0.f); acc2[j].w = fmaxf(acc2[j].w, 0.f);
                }
            }
        }
#pragma unroll
        for (int j = 0; j < RPT; ++j) {
            int r = rg + j;
            if (r < nrows) {
                *(float4*)&out[(tile + r) * 64 + c0] = acc[j];
                if (DUAL) *(float4*)&out2[(tile + r) * 64 + c0] = acc2[j];
            }
        }
        if (STATS) {
            if (threadIdx.x < SS) sStat[threadIdx.x] = 0.f;
            __syncthreads();
            float sx = 0, sy = 0, sz = 0, sw = 0, qx = 0, qy = 0, qz = 0, qw = 0;
            float sx2 = 0, sy2 = 0, sz2 = 0, sw2 = 0, qx2 = 0, qy2 = 0, qz2 = 0, qw2 = 0;
#pragma unroll
            for (int j = 0; j < RPT; ++j) {
                if (rg + j < nrows) {
                    sx += acc[j].x; sy += acc[j].y; sz += acc[j].z; sw += acc[j].w;
                    qx += acc[j].x * acc[j].x; qy += acc[j].y * acc[j].y;
                    qz += acc[j].z * acc[j].z; qw += acc[j].w * acc[j].w;
                    if (DUAL) {
                        sx2 += acc2[j].x; sy2 += acc2[j].y; sz2 += acc2[j].z; sw2 += acc2[j].w;
                        qx2 += acc2[j].x * acc2[j].x; qy2 += acc2[j].y * acc2[j].y;
                        qz2 += acc2[j].z * acc2[j].z; qw2 += acc2[j].w * acc2[j].w;
                    }
                }
            }
            atomicAdd(&sStat[c0 + 0], sx); atomicAdd(&sStat[c0 + 1], sy);
            atomicAdd(&sStat[c0 + 2], sz); atomicAdd(&sStat[c0 + 3], sw);
            atomicAdd(&sStat[64 + c0 + 0], qx); atomicAdd(&sStat[64 + c0 + 1], qy);
            atomicAdd(&sStat[64 + c0 + 2], qz); atomicAdd(&sStat[64 + c0 + 3], qw);
            if (DUAL) {
                atomicAdd(&sStat[128 + c0 + 0], sx2); atomicAdd(&sStat[128 + c0 + 1], sy2);
                atomicAdd(&sStat[128 + c0 + 2], sz2); atomicAdd(&sStat[128 + c0 + 3], sw2);
                atomicAdd(&sStat[192 + c0 + 0], qx2); atomicAdd(&sStat[192 + c0 + 1], qy2);
                atomicAdd(&sStat[192 + c0 + 2], qz2); atomicAdd(&sStat[192 + c0 + 3], qw2);
            }
            __syncthreads();
            if (threadIdx.x < 128) atomicAdd(&gstats[threadIdx.x], sStat[threadIdx.x]);
            if (DUAL && threadIdx.x >= 128) atomicAdd(&gstats2[threadIdx.x - 128], sStat[threadIdx.x]);
        }
    }
}

// ---------------- batchnorm apply ----------------

__global__ void bn_apply_k(const float* __restrict__ in, float* __restrict__ out, int rows,
                           const float* __restrict__ stats, const float* __restrict__ gamma,
                           const float* __restrict__ beta) {
    int n = rows * 64;
    float invr = 1.f / (float)rows;
    for (int i = blockIdx.x * blockDim.x + threadIdx.x; i < n; i += gridDim.x * blockDim.x) {
        int c = i & 63;
        float m   = stats[c] * invr;
        float var = stats[64 + c] * invr - m * m;
        out[i] = (in[i] - m) * rsqrtf(var + 1e-5f) * gamma[c] + beta[c];
    }
}

// ---------------- segment boundaries (batch is sorted) ----------------

__global__ void seg_bounds_k(const int* __restrict__ batch, int* __restrict__ segstart) {
    int g = blockIdx.x * blockDim.x + threadIdx.x;
    if (g > GG) return;
    int lo = 0, hi = NN;
    while (lo < hi) {
        int mid = (lo + hi) >> 1;
        if (batch[mid] < g) lo = mid + 1; else hi = mid;
    }
    segstart[g] = lo;
}

// ---------------- mean pooling with fused BN affine: slots = a*mean(z)+d ----------------

__global__ __launch_bounds__(256) void graph_mean_bn_k(const float* __restrict__ z,
                                                       const int* __restrict__ segst,
                                                       const float* __restrict__ stats,
                                                       const float* __restrict__ gamma,
                                                       const float* __restrict__ beta,
                                                       float* __restrict__ slots) {
    int g = blockIdx.x, tid = threadIdx.x, w = tid >> 6, lane = tid & 63;
    int s0 = segst[g], s1 = segst[g + 1];
    float acc = 0.f;
    for (int n = s0 + w; n < s1; n += 4) acc += z[n * 64 + lane];
    __shared__ float red[256];
    red[tid] = acc;
    __syncthreads();
    if (tid < 64) {
        float m   = stats[tid] * (1.f / NN);
        float var = stats[64 + tid] * (1.f / NN) - m * m;
        float a   = rsqrtf(var + 1e-5f) * gamma[tid];
        float d   = beta[tid] - m * a;
        float mean = (red[tid] + red[64 + tid] + red[128 + tid] + red[192 + tid])
                   / (float)max(s1 - s0, 1);
        slots[g * 64 + tid] = a * mean + d;
    }
}

// ---------------- fused attention iteration: q -> logits -> softmax -> updates -> GRU ----------------

__global__ __launch_bounds__(256) void attn_iter_k(
    const float* __restrict__ kbuf, const float* __restrict__ vbuf,
    float* __restrict__ slots, const int* __restrict__ segst,
    const float* __restrict__ Wq,
    const float* __restrict__ Wih, const float* __restrict__ Whh,
    const float* __restrict__ bih, const float* __restrict__ bhh,
    float* __restrict__ attn, int final_iter)
{
    int g = blockIdx.x, tid = threadIdx.x, w = tid >> 6, lane = tid & 63;
    __shared__ float ssl[64], sq[64], sred[256], supd[64], ssum[4];
    __shared__ float sgi[192], sgh[192];
    __shared__ float smax, sstot;

    if (tid < 64) ssl[tid] = slots[g * 64 + tid];
    __syncthreads();
    // q = slots[g] @ Wq  (each wave does 16 of the K terms)
    {
        float p = 0.f;
#pragma unroll
        for (int kk = 0; kk < 16; ++kk) p += ssl[w * 16 + kk] * Wq[(w * 16 + kk) * 64 + lane];
        sred[tid] = p;
    }
    __syncthreads();
    if (tid < 64) sq[tid] = sred[tid] + sred[64 + tid] + sred[128 + tid] + sred[192 + tid];
    __syncthreads();

    int s0 = segst[g], s1 = segst[g + 1];
    float qd = sq[lane];

    // pass 1: logits (stored raw in attn[]) + max
    float m = -INFINITY;
    for (int n = s0 + w; n < s1; n += 4) {
        float p = kbuf[n * 64 + lane] * qd;
        p += __shfl_xor(p, 1);  p += __shfl_xor(p, 2);  p += __shfl_xor(p, 4);
        p += __shfl_xor(p, 8);  p += __shfl_xor(p, 16); p += __shfl_xor(p, 32);
        p *= 0.125f;  // 1/sqrt(64)
        if (lane == 0) attn[n] = p;
        m = fmaxf(m, p);
    }
    if (lane == 0) sred[w] = m;
    __syncthreads();
    if (tid == 0) smax = fmaxf(fmaxf(sred[0], sred[1]), fmaxf(sred[2], sred[3]));
    __syncthreads();
    m = smax;

    // pass 2: e = exp(l-m) (stored in attn[]), sum + weighted v accumulation
    float s = 0.f, upd = 0.f;
    for (int n = s0 + w; n < s1; n += 4) {
        float e = expf(attn[n] - m);
        if (lane == 0) attn[n] = e;
        s += e;
        upd += e * vbuf[n * 64 + lane];
    }
    sred[tid] = upd;
    if (lane == 0) ssum[w] = s;
    __syncthreads();
    if (tid < 64) {
        float st = ssum[0] + ssum[1] + ssum[2] + ssum[3] + 1e-9f;
        if (tid == 0) sstot = st;
        supd[tid] = (sred[tid] + sred[64 + tid] + sred[128 + tid] + sred[192 + tid]) / st;
    }
    __syncthreads();

    if (final_iter) {
        float inv = 1.f / sstot;
        for (int n = s0 + tid; n < s1; n += 256) attn[n] *= inv;
    }

    // GRU: slots = (1-z)*n + z*h
    if (tid < 192) {
        float a = bih[tid], b = bhh[tid];
        const float* wi = &Wih[tid * 64];
        const float* wh = &Whh[tid * 64];
#pragma unroll 8
        for (int j = 0; j < 64; ++j) { a += supd[j] * wi[j]; b += ssl[j] * wh[j]; }
        sgi[tid] = a; sgh[tid] = b;
    }
    __syncthreads();
    if (tid < 64) {
        float r  = 1.f / (1.f + expf(-(sgi[tid] + sgh[tid])));
        float z  = 1.f / (1.f + expf(-(sgi[64 + tid] + sgh[64 + tid])));
        float nn = tanhf(sgi[128 + tid] + r * sgh[128 + tid]);
        slots[g * 64 + tid] = (1.f - z) * nn + z * ssl[tid];
    }
}

// ---------------- host side ----------------

extern "C" void kernel_launch(void* const* d_in, const int* in_sizes, int n_in,
                              void* d_out, int out_size, void* d_ws, size_t ws_size,
                              hipStream_t stream) {
    (void)in_sizes; (void)n_in; (void)out_size; (void)ws_size;

    const float* x      = (const float*)d_in[0];
    const int*   ei     = (const int*)d_in[1];
    const int*   srcI   = ei;
    const int*   dstI   = ei + EE;
    const int*   batch  = (const int*)d_in[2];
    const float* noise  = (const float*)d_in[3];
    const float* W1_0   = (const float*)d_in[4];
    const float* b1_0   = (const float*)d_in[5];
    const float* W2_0   = (const float*)d_in[6];
    const float* b2_0   = (const float*)d_in[7];
    const float* W1_r   = (const float*)d_in[8];
    const float* b1_r   = (const float*)d_in[9];
    const float* W2_r   = (const float*)d_in[10];
    const float* b2_r   = (const float*)d_in[11];
    const float* bn_g   = (const float*)d_in[12];
    const float* bn_b   = (const float*)d_in[13];
    const float* Wq     = (const float*)d_in[14];
    const float* Wk     = (const float*)d_in[15];
    const float* Wv     = (const float*)d_in[16];
    const float* Wih    = (const float*)d_in[17];
    const float* Whh    = (const float*)d_in[18];
    const float* bih    = (const float*)d_in[19];
    const float* bhh    = (const float*)d_in[20];
    const float* nmW    = (const float*)d_in[21];
    const float* nmb    = (const float*)d_in[22];
    const float* nlW    = (const float*)d_in[23];
    const float* nlb    = (const float*)d_in[24];
    const float* gmW    = (const float*)d_in[25];
    const float* gmb    = (const float*)d_in[26];
    const float* glW    = (const float*)d_in[27];
    const float* glb    = (const float*)d_in[28];
    const float* pj_g   = (const float*)d_in[29];
    const float* pj_b   = (const float*)d_in[30];

    float* ws      = (float*)d_ws;
    float* B0      = ws;                       // NN*DD
    float* B1      = B0 + NN * DD;             // NN*DD
    float* B2      = B1 + NN * DD;             // NN*DD
    float* slots   = B2 + NN * DD;             // GG*DD
    float* gpre1   = slots + GG * DD;          // GG*DD
    float* gpre2   = gpre1 + GG * DD;          // GG*DD
    float* attn    = gpre2 + GG * DD;          // NN
    float* stats   = attn + NN;                // 7*128
    int*   segst   = (int*)(stats + 7 * 128);  // GG+1
    int*   rowst   = segst + GG + 1;           // NN+1
    int*   cursor  = rowst + NN + 1;           // NN
    int*   bsum    = cursor + NN;              // 64
    int*   bofs    = bsum + 64;                // 64
    int*   csr_src = bofs + 64;                // EE

    float* s0 = stats, *s1 = stats + 128, *s2 = stats + 256, *s3 = stats + 384,
         * s4 = stats + 512, *s5 = stats + 640, *s6 = stats + 768;

    float* outp = (float*)d_out;
    float* out_nmu = outp;
    float* out_nlv = outp + NN * DD;
    float* out_gmu = outp + 2 * NN * DD;
    float* out_glv = outp + 2 * NN * DD + GG * DD;

    constexpr int NB = (NN + 1023) / 1024;  // 49 scan chunks
    constexpr int GE4 = (EE / 4 + 255) / 256;

#define GK(...) <<<__VA_ARGS__, 0, stream>>>
    // ---------- init + CSR build + segments ----------
    zero_all_k GK((NN + 255) / 256, 256)(cursor, stats);
    hist_k GK(GE4, 256)(dstI, cursor);
    scanA_k GK(NB, 1024)(cursor, rowst, bsum);
    scanB_k GK(1, 64)(bsum, bofs, NB);
    scanC_k GK((NN + 255) / 256, 256)(rowst, bofs, cursor);
    fill_k GK(GE4, 256)(srcI, dstI, cursor, csr_src);
    seg_bounds_k GK(3, 256)(batch, segst);

    // ---------- GIN layer 0 (GEMM-first: gather on 64-wide) ----------
    gemm_k<128, false, false, false, false, false, false> GK(1563, 256)
        (x, W1_0, nullptr, nullptr, nullptr, B0, nullptr, NN, nullptr, nullptr, nullptr, nullptr, nullptr, nullptr, nullptr);
    gin_agg_br_k GK(3125, 256)(B0, rowst, csr_src, b1_0, B1);
    gemm_k<64, true, true, true, false, false, false> GK(782, 256)
        (B1, W2_0, nullptr, b2_0, nullptr, B2, nullptr, NN, s0, nullptr, nullptr, nullptr, nullptr, nullptr, nullptr);

    // ---------- GIN layer 1 (BN0 affine fused into GEMM input) ----------
    gemm_k<64, false, false, false, false, true, false> GK(782, 256)
        (B2, W1_r, nullptr, nullptr, nullptr, B0, nullptr, NN, nullptr, nullptr, nullptr, nullptr, s0, bn_g + 0, bn_b + 0);
    gin_agg_br_k GK(3125, 256)(B0, rowst, csr_src, b1_r, B1);
    gemm_k<64, true, true, true, false, false, false> GK(782, 256)
        (B1, W2_r, nullptr, b2_r, nullptr, B2, nullptr, NN, s1, nullptr, nullptr, nullptr, nullptr, nullptr, nullptr);

    // ---------- GIN layer 2 ----------
    gemm_k<64, false, false, false, false, true, false> GK(782, 256)
        (B2, W1_r + DD * DD, nullptr, nullptr, nullptr, B0, nullptr, NN, nullptr, nullptr, nullptr, nullptr, s1, bn_g + 64, bn_b + 64);
    gin_agg_br_k GK(3125, 256)(B0, rowst, csr_src, b1_r + DD, B1);
    gemm_k<64, true, true, true, false, false, false> GK(782, 256)
        (B1, W2_r + DD * DD, nullptr, b2_r + DD, nullptr, B2, nullptr, NN, s2, nullptr, nullptr, nullptr, nullptr, nullptr, nullptr);
    // B2 = z2 (pre-BN); final BN affine (s2, bn[2]) fused into all consumers.

    // ---------- summary maker ----------
    graph_mean_bn_k GK(GG, 256)(B2, segst, s2, bn_g + 128, bn_b + 128, slots);
    gemm_k<64, false, false, false, false, true, true> GK(782, 256)   // k,v in one pass
        (B2, Wk, Wv, nullptr, nullptr, B0, B1, NN, nullptr, nullptr, nullptr, nullptr, s2, bn_g + 128, bn_b + 128);
    attn_iter_k GK(GG, 256)(B0, B1, slots, segst, Wq, Wih, Whh, bih, bhh, attn, 0);
    attn_iter_k GK(GG, 256)(B0, B1, slots, segst, Wq, Wih, Whh, bih, bhh, attn, 1);

    // ---------- node heads (noisy + BN-affine fused into DUAL GEMM) ----------
    gemm_k<64, true, true, true, true, true, true> GK(782, 256)
        (B2, nmW, nlW, nmb, nlb, B0, B1, NN, s3, s4, attn, noise, s2, bn_g + 128, bn_b + 128);
    bn_apply_k GK(2048, 256)(B0, out_nmu, NN, s3, pj_g + 0, pj_b + 0);
    bn_apply_k GK(2048, 256)(B1, out_nlv, NN, s4, pj_g + 64, pj_b + 64);

    // ---------- graph heads ----------
    gemm_k<64, true, true, true, false, false, true> GK(8, 256)
        (slots, gmW, glW, gmb, glb, gpre1, gpre2, GG, s5, s6, nullptr, nullptr, nullptr, nullptr, nullptr);
    bn_apply_k GK(128, 256)(gpre1, out_gmu, GG, s5, pj_g + 128, pj_b + 128);
    bn_apply_k GK(128, 256)(gpre2, out_glv, GG, s6, pj_g + 192, pj_b + 192);
#undef GK
}